// Round 6
// baseline (34.553 us; speedup 1.0000x reference)
//
#include <hip/hip_runtime.h>

#define S_LEN 4096
#define DIM   64
#define HALF  50
#define RB    256           // query rows per block
#define WQ    16            // query rows per wave (16 waves)
#define THREADS 1024
#define KCAP  384           // staged V keys: kstart = r0-64 (32-aligned), span <= 370
#define NT    5             // max 32-key tiles per wave (static unroll, reg P)
#define SCALE 0.125f

typedef __attribute__((ext_vector_type(8))) short bf16x8;
typedef __attribute__((ext_vector_type(4))) float f32x4;

__device__ __forceinline__ unsigned int bf16_rne(float f) {
    unsigned int u = __float_as_uint(f);
    return (u + 0x7fffu + ((u >> 16) & 1u)) >> 16;
}
__device__ __forceinline__ unsigned int pk2(float lo, float hi) {
    return bf16_rne(lo) | (bf16_rne(hi) << 16);
}
__device__ __forceinline__ bf16x8 cvt8(float4 a, float4 b) {
    uint4 t = make_uint4(pk2(a.x, a.y), pk2(a.z, a.w), pk2(b.x, b.y), pk2(b.z, b.w));
    return __builtin_bit_cast(bf16x8, t);
}

// LDS: V^T [64 d][384 keys] bf16, slot' = slot ^ (d&7) ^ ((d>>3)&7)   (48KB)
//      P   [16 waves][16 q][40 k] bf16 per-wave scratch               (20KB)
// K is NOT staged: QK^T streams K global->reg (L1/L2-served) while V staging
// is in flight; P parked in registers; ONE barrier; then PV from LDS.
__global__ __launch_bounds__(THREADS, 4)
void lattn_mfma(const float* __restrict__ Q, const float* __restrict__ K,
                const float* __restrict__ V, float* __restrict__ O) {
    __shared__ unsigned short Vs[DIM * KCAP];
    __shared__ unsigned short Ps[16 * 16 * 40];

    // bijective XCD swizzle: consecutive r0-blocks (overlapping halos) share an XCD L2
    const int nwg = gridDim.x;                 // 256
    const int cpx = nwg >> 3;
    const int bid = blockIdx.x;
    const int logical = (bid & 7) * cpx + (bid >> 3);
    const int bh = logical >> 4;               // 16 x-blocks per bh
    const int r0 = (logical & 15) * RB;

    const size_t base = (size_t)bh * (S_LEN * DIM);
    const float* Qg = Q + base;
    const float* Kg = K + base;
    const float* Vg = V + base;
    float*       Og = O + base;

    const int kstart = (r0 >= HALF) ? ((r0 - HALF) & ~31) : 0;
    const int kend   = min(S_LEN, r0 + RB + HALF);         // exclusive
    const int nkeys  = ((kend - kstart + 31) >> 5) << 5;   // 320 or 384

    const int u = threadIdx.x;
    const int lane = u & 63;
    const int wv_  = u >> 6;
    const int g  = lane >> 4;
    const int cc = lane & 15;
    const int qlo = r0 + WQ * wv_;

    // ---- stage V -> transposed bf16 LDS (static write order; swizzle spreads banks) ----
    for (int idx = u; idx < (nkeys << 2); idx += THREADS) {
        const int kp = idx >> 3;                 // key-pair index
        const int m  = idx & 7;                  // d-octet owner
        const int d0 = m * 8;
        const int k0 = kp * 2;
        const int kg = kstart + k0;
        float a0[8], a1[8];
        if (kg < kend) {                          // kend even -> pair never straddles
            const float* va = Vg + (size_t)kg * DIM + d0;
            *(float4*)a0 = *(const float4*)va;        *(float4*)(a0 + 4) = *(const float4*)(va + 4);
            *(float4*)a1 = *(const float4*)(va + DIM); *(float4*)(a1 + 4) = *(const float4*)(va + DIM + 4);
        } else {
            #pragma unroll
            for (int j = 0; j < 8; ++j) { a0[j] = 0.f; a1[j] = 0.f; }
        }
        #pragma unroll
        for (int j = 0; j < 8; ++j) {            // static index j; m-sharers split banks via (d>>3)&7 = m
            const int d  = d0 + j;
            const int sl = (k0 >> 3) ^ (d & 7) ^ ((d >> 3) & 7);
            *(unsigned int*)(Vs + d * KCAP + sl * 8 + (k0 & 7)) = pk2(a0[j], a1[j]);
        }
    }

    // ---- Q^T B-fragments straight from global (scale folded) ----
    bf16x8 qf[2];
    #pragma unroll
    for (int ds = 0; ds < 2; ++ds) {
        const float* src = Qg + (size_t)(qlo + cc) * DIM + ds * 32 + g * 8;
        float4 a = *(const float4*)src;
        float4 b = *(const float4*)(src + 4);
        a.x *= SCALE; a.y *= SCALE; a.z *= SCALE; a.w *= SCALE;
        b.x *= SCALE; b.y *= SCALE; b.z *= SCALE; b.w *= SCALE;
        qf[ds] = cvt8(a, b);
    }

    // per-wave tile range on the block's 32-key grid
    int lo = (qlo >= HALF) ? (qlo - HALF) : 0;
    lo = max(kstart, lo & ~31);
    const int t0 = (lo - kstart) >> 5;
    const int hi = min(kend, qlo + WQ - 1 + HALF + 1);
    const int t1 = (hi - kstart + 31) >> 5;

    unsigned short* Pw = Ps + wv_ * (16 * 40);
    float denom = 0.f;
    bf16x8 pfr[NT];          // static-indexed (unrolled) -> registers

    // ---- QK^T + softmax for ALL tiles, K streamed global->reg (V stage in flight) ----
    #pragma unroll
    for (int i = 0; i < NT; ++i) {
        const int st = t0 + i;
        if (st < t1) {
            const int kb32 = st << 5;

            // load K tile fragments: rows kstart+kb32+kt*16+cc, cols ds*32+g*8..+8
            bf16x8 ka[2][2];
            #pragma unroll
            for (int kt = 0; kt < 2; ++kt) {
                const int krow = kstart + kb32 + kt * 16 + cc;
                if (krow < kend) {
                    const float* kp_ = Kg + (size_t)krow * DIM + g * 8;
                    const float4 a0 = *(const float4*)kp_;
                    const float4 a1 = *(const float4*)(kp_ + 4);
                    const float4 b0 = *(const float4*)(kp_ + 32);
                    const float4 b1 = *(const float4*)(kp_ + 36);
                    ka[0][kt] = cvt8(a0, a1);
                    ka[1][kt] = cvt8(b0, b1);
                } else {
                    uint4 z = make_uint4(0u, 0u, 0u, 0u);
                    ka[0][kt] = __builtin_bit_cast(bf16x8, z);
                    ka[1][kt] = __builtin_bit_cast(bf16x8, z);
                }
            }

            // swapped QK^T: S^T[key][q]
            f32x4 sacc[2] = {};
            #pragma unroll
            for (int ds = 0; ds < 2; ++ds) {
                #pragma unroll
                for (int kt = 0; kt < 2; ++kt)
                    sacc[kt] = __builtin_amdgcn_mfma_f32_16x16x32_bf16(ka[ds][kt], qf[ds], sacc[kt], 0, 0, 0);
            }

            // mask + exp + P layout shuffle (per-wave LDS, wave-internal sync only)
            const int q = qlo + cc;
            #pragma unroll
            for (int kt = 0; kt < 2; ++kt) {
                float w4[4];
                const int keyb = kstart + kb32 + kt * 16 + g * 4;
                #pragma unroll
                for (int r = 0; r < 4; ++r) {
                    const int key = keyb + r;
                    const float e = __expf(fminf(sacc[kt][r], 60.f));
                    const int dd  = key - q;
                    const bool ok = (dd >= -HALF) && (dd <= HALF) && (key < S_LEN);
                    w4[r] = ok ? e : 0.f;
                    denom += w4[r];
                }
                *(uint2*)(Pw + cc * 40 + kt * 16 + g * 4) =
                    make_uint2(pk2(w4[0], w4[1]), pk2(w4[2], w4[3]));
            }
            pfr[i] = *(const bf16x8*)(Pw + cc * 40 + g * 8);
        }
    }

    __syncthreads();   // V^T now staged

    // ---- PV from LDS: O^T += V^T x P ----
    f32x4 oacc[4] = {};
    #pragma unroll
    for (int i = 0; i < NT; ++i) {
        const int st = t0 + i;
        if (st < t1) {
            const int kb32 = st << 5;
            #pragma unroll
            for (int dt = 0; dt < 4; ++dt) {
                const int d  = dt * 16 + cc;
                const int sl = ((kb32 >> 3) + g) ^ (d & 7) ^ ((d >> 3) & 7);
                const bf16x8 vf = *(const bf16x8*)(Vs + d * KCAP + sl * 8);
                oacc[dt] = __builtin_amdgcn_mfma_f32_16x16x32_bf16(vf, pfr[i], oacc[dt], 0, 0, 0);
            }
        }
    }

    // ---- normalize + store ----
    denom += __shfl_xor(denom, 16);
    denom += __shfl_xor(denom, 32);
    const float rinv = 1.f / denom;
    float* dst = Og + (size_t)(qlo + cc) * DIM;
    #pragma unroll
    for (int dt = 0; dt < 4; ++dt) {
        const f32x4 o = oacc[dt];
        *(float4*)(dst + dt * 16 + g * 4) =
            make_float4(o[0] * rinv, o[1] * rinv, o[2] * rinv, o[3] * rinv);
    }
}

extern "C" void kernel_launch(void* const* d_in, const int* in_sizes, int n_in,
                              void* d_out, int out_size, void* d_ws, size_t ws_size,
                              hipStream_t stream) {
    const float* q = (const float*)d_in[0];
    const float* k = (const float*)d_in[1];
    const float* v = (const float*)d_in[2];
    float* o = (float*)d_out;
    const int nbh = in_sizes[0] / (S_LEN * DIM);      // B*H = 16
    dim3 grid((S_LEN / RB) * nbh);                    // 256 blocks
    lattn_mfma<<<grid, THREADS, 0, stream>>>(q, k, v, o);
}